// Round 26
// baseline (137.767 us; speedup 1.0000x reference)
//
#include <hip/hip_runtime.h>
#include <hip/hip_bf16.h>

#define NN 10000
#define NE 320000
#define FDIM 128
#define NRBF 20
#define PHI_DIM 384
#define NBUCK 4
#define NKEY (NN * NBUCK)     // 40000, key = bucket*NN + i (bucket-major)
#define SCAN_BLOCKS 157       // 157*256 = 40192 >= NKEY+1

typedef unsigned int uint;
typedef unsigned short ushort;
typedef __bf16 bf16x8 __attribute__((ext_vector_type(8)));
typedef float f32x4 __attribute__((ext_vector_type(4)));

#if __has_builtin(__builtin_amdgcn_fdot2_f32_bf16)
#define USE_DOT2 1
typedef __bf16 bf16x2 __attribute__((ext_vector_type(2)));
#else
#define USE_DOT2 0
#endif

__device__ __forceinline__ ushort f2bf(float x) {
  __hip_bfloat16 b = __float2bfloat16(x);
  return *(ushort*)&b;
}
__device__ __forceinline__ float bflo(uint u) { return __uint_as_float(u << 16); }
__device__ __forceinline__ float bfhi(uint u) { return __uint_as_float(u & 0xffff0000u); }
__device__ __forceinline__ float bf2f(ushort u) { return __uint_as_float(((uint)u) << 16); }
__device__ __forceinline__ int jbucket(int j) { return (int)(((uint)j * NBUCK) / NN); }

// tab row (1280 B): [0,512) uint wy|wx ; [512,1024) uint phi1|wz ; [1024,1280) ushort phi2
// edata record (48 B): dword0 = dy|dx ; dword1..10 = (rbf*c) pairs ; dword11 = dz|c
// offsets[] PARTIAL (within-scan1-block); final = offsets[k] + blocksums[k>>8];
// offsets[NKEY] written FINAL by scan2.
// W1p/W2p: frag-packed bf16 weights: [(ks*4+g)*COLS + n] -> 8 bf16 of rows ks*32+g*8+e.

// ---------------- weight pre-pack: f32 -> frag-friendly bf16 ----------------
__global__ void wconv_kernel(const float* __restrict__ W1, const float* __restrict__ W2,
                             ushort* __restrict__ W1p, ushort* __restrict__ W2p) {
  const int gid = blockIdx.x * 256 + threadIdx.x;  // 8192 total
  if (gid < 2048) {  // W1: 4*4*128 groups
    const int n = gid & 127, g = (gid >> 7) & 3, ks = gid >> 9;
    ushort* dst = W1p + gid * 8;
#pragma unroll
    for (int e = 0; e < 8; e++) dst[e] = f2bf(W1[(ks * 32 + g * 8 + e) * FDIM + n]);
  } else {  // W2: 4*4*384 groups
    const int q = gid - 2048;
    const int ks = q / 1536;
    const int rem = q - ks * 1536;
    const int g = rem / 384;
    const int n = rem - g * 384;
    ushort* dst = W2p + q * 8;
#pragma unroll
    for (int e = 0; e < 8; e++) dst[e] = f2bf(W2[(ks * 32 + g * 8 + e) * PHI_DIM + n]);
  }
}

// ------- node MLP via MFMA: 625 blocks x 256 thr (4 waves), 16 nodes/block -------
// A layout (verified r17): row=lane&15, k=(lane>>4)*8+[0,8) ; B: col=lane&15, same k
// D: col=lane&15, row=(lane>>4)*4+reg
__global__ __launch_bounds__(256) void phi_kernel(
    const float* __restrict__ S, const float* __restrict__ b1, const float* __restrict__ b2,
    const float* __restrict__ vf, const int* __restrict__ idx_i, const int* __restrict__ idx_j,
    int* __restrict__ counts, const ushort* __restrict__ W1p, const ushort* __restrict__ W2p,
    char* __restrict__ tab) {
  __shared__ ushort Hb[16][136];  // padded: row stride 272 B
  __shared__ ushort Pb[16][392];  // padded: row stride 784 B
  const int t = threadIdx.x;
  const int lane = t & 63;
  const int wv = t >> 6;        // 0..3
  const int mrow = lane & 15;   // A-row (node) / B,D-col
  const int kg = lane >> 4;     // 0..3 (k-group)
  // fused: edge counting (2 edges/thread: 625*256*2 == NE)
  {
    const int e0 = (blockIdx.x * 256 + t) * 2;
    atomicAdd(&counts[jbucket(idx_j[e0]) * NN + idx_i[e0]], 1);
    atomicAdd(&counts[jbucket(idx_j[e0 + 1]) * NN + idx_i[e0 + 1]], 1);
  }
  const int n0 = blockIdx.x * 16;
  // A-frags from S (f32 -> bf16)
  bf16x8 sfrag[4];
#pragma unroll
  for (int ks = 0; ks < 4; ks++) {
    const float* sp = S + (size_t)(n0 + mrow) * FDIM + ks * 32 + kg * 8;
    float4 v0 = *(const float4*)sp;
    float4 v1 = *(const float4*)(sp + 4);
    uint w0 = ((uint)f2bf(v0.y) << 16) | f2bf(v0.x);
    uint w1 = ((uint)f2bf(v0.w) << 16) | f2bf(v0.z);
    uint w2 = ((uint)f2bf(v1.y) << 16) | f2bf(v1.x);
    uint w3 = ((uint)f2bf(v1.w) << 16) | f2bf(v1.z);
    sfrag[ks] = __builtin_bit_cast(bf16x8, make_uint4(w0, w1, w2, w3));
  }
  // layer 1: H = silu(S@W1 + b1), wave wv computes feat cols [wv*32, wv*32+32)
#pragma unroll
  for (int tile = 0; tile < 2; tile++) {
    const int nc = wv * 32 + tile * 16 + mrow;  // feature col
    f32x4 acc = {0.f, 0.f, 0.f, 0.f};
#pragma unroll
    for (int ks = 0; ks < 4; ks++) {
      bf16x8 bfrag = __builtin_bit_cast(
          bf16x8, *(const uint4*)(W1p + ((size_t)(ks * 4 + kg) * FDIM + nc) * 8));
      acc = __builtin_amdgcn_mfma_f32_16x16x32_bf16(sfrag[ks], bfrag, acc, 0, 0, 0);
    }
    const float bb = b1[nc];
#pragma unroll
    for (int r = 0; r < 4; r++) {
      const float x = acc[r] + bb;
      Hb[kg * 4 + r][nc] = f2bf(x / (1.0f + expf(-x)));
    }
  }
  __syncthreads();
  // layer 2: phi = H@W2 + b2, wave wv computes cols [wv*96, wv*96+96)
  bf16x8 hfrag[4];
#pragma unroll
  for (int ks = 0; ks < 4; ks++)
    hfrag[ks] = __builtin_bit_cast(bf16x8, *(const uint4*)&Hb[mrow][ks * 32 + kg * 8]);
#pragma unroll
  for (int tile = 0; tile < 6; tile++) {
    const int nc = wv * 96 + tile * 16 + mrow;  // phi col 0..383
    f32x4 acc = {0.f, 0.f, 0.f, 0.f};
#pragma unroll
    for (int ks = 0; ks < 4; ks++) {
      bf16x8 bfrag = __builtin_bit_cast(
          bf16x8, *(const uint4*)(W2p + ((size_t)(ks * 4 + kg) * PHI_DIM + nc) * 8));
      acc = __builtin_amdgcn_mfma_f32_16x16x32_bf16(hfrag[ks], bfrag, acc, 0, 0, 0);
    }
    const float bb = b2[nc];
#pragma unroll
    for (int r = 0; r < 4; r++) Pb[kg * 4 + r][nc] = f2bf(acc[r] + bb);
  }
  __syncthreads();
  // pack phase: w* = vf*·phi0 precompute + tab row assembly (16 nodes x 128 feats)
#pragma unroll
  for (int c = 0; c < 8; c++) {
    const int idx = c * 256 + t;
    const int nd = idx >> 7;
    const int f = idx & 127;
    const int node = n0 + nd;
    const float p0 = bf2f(Pb[nd][f]);
    const uint p1u = Pb[nd][f + 128];
    const ushort p2u = Pb[nd][f + 256];
    const float* src = vf + (size_t)node * (FDIM * 3) + f * 3;
    const uint wx = f2bf(src[0] * p0);
    const uint wy = f2bf(src[1] * p0);
    const uint wz = f2bf(src[2] * p0);
    char* pb = tab + (size_t)node * 1280;
    ((uint*)pb)[f] = (wy << 16) | wx;
    ((uint*)(pb + 512))[f] = (p1u << 16) | wz;
    ((ushort*)(pb + 1024))[f] = p2u;
  }
}

// ---------------- scan: per-block partials + block-sum scan ----------------
__global__ void scan1_kernel(const int* __restrict__ counts, int* __restrict__ offsets,
                             int* __restrict__ blocksums) {
  __shared__ int s[256];
  const int t = threadIdx.x;
  const int idx = blockIdx.x * 256 + t;
  const int c = counts[idx];  // region zero-padded to 40960
  s[t] = c;
  __syncthreads();
  for (int off = 1; off < 256; off <<= 1) {
    int v = (t >= off) ? s[t - off] : 0;
    __syncthreads();
    s[t] += v;
    __syncthreads();
  }
  if (idx < NKEY) offsets[idx] = s[t] - c;  // exclusive WITHIN block (partial)
  if (t == 255) blocksums[blockIdx.x] = s[255];
}

__global__ void scan2_kernel(int* __restrict__ blocksums, int* __restrict__ offsets) {
  __shared__ int s[256];
  const int t = threadIdx.x;  // 256 threads
  int v0 = (t < SCAN_BLOCKS) ? blocksums[t] : 0;
  s[t] = v0;
  __syncthreads();
  for (int off = 1; off < 256; off <<= 1) {
    int v = (t >= off) ? s[t - off] : 0;
    __syncthreads();
    s[t] += v;
    __syncthreads();
  }
  if (t < SCAN_BLOCKS) blocksums[t] = s[t] - v0;  // exclusive base per block
  if (t == 255) offsets[NKEY] = s[t];             // FINAL total = NE
}

// ---------------- stage CSR-ordered (bucket-major): jlist + 48-B records ----------------
__global__ void stage_kernel(const int* __restrict__ idx_i, const int* __restrict__ idx_j,
                             const float* __restrict__ cut, const float* __restrict__ dir,
                             const float* __restrict__ rbf, const int* __restrict__ offsets,
                             const int* __restrict__ blocksums, int* __restrict__ counts,
                             uint* __restrict__ edata, int* __restrict__ jlist) {
  int e = blockIdx.x * blockDim.x + threadIdx.x;
  if (e >= NE) return;
  const int j = idx_j[e];
  const int key = jbucket(j) * NN + idx_i[e];
  int pos = atomicSub(&counts[key], 1) - 1;
  const int slot = offsets[key] + blocksums[key >> 8] + pos;
  jlist[slot] = j;
  const float c = cut[e];
  uint w[12];
  w[0] = ((uint)f2bf(dir[e * 3 + 1]) << 16) | f2bf(dir[e * 3 + 0]);
  const float* rb = rbf + (size_t)e * NRBF;
#pragma unroll
  for (int r = 0; r < 10; r++) {
    uint lo = (uint)f2bf(rb[2 * r] * c);
    uint hi = (uint)f2bf(rb[2 * r + 1] * c);
    w[1 + r] = (hi << 16) | lo;
  }
  w[11] = ((uint)f2bf(dir[e * 3 + 2]) << 16) | f2bf(c);
  uint4* d = (uint4*)(edata + (size_t)slot * 12);
  d[0] = make_uint4(w[0], w[1], w[2], w[3]);
  d[1] = make_uint4(w[4], w[5], w[6], w[7]);
  d[2] = make_uint4(w[8], w[9], w[10], w[11]);
}

// ---- node: 1 node / 128-thread block, 4 bucket-segments, 2-deep pipeline ----
__global__ __launch_bounds__(128, 5) void node_kernel(
    const uint* __restrict__ edata, const int* __restrict__ jlist,
    const float* __restrict__ Wr, const float* __restrict__ br,
    const char* __restrict__ tab, const float* __restrict__ sf,
    const float* __restrict__ vf, const int* __restrict__ offsets,
    const int* __restrict__ blocksums, float* __restrict__ out) {
  const int f = threadIdx.x;  // 0..127
#if USE_DOT2
  bf16x2 wrA[11], wrB[11], wrC[11];
#pragma unroll
  for (int r = 0; r < 10; r++) {
    uint a = ((uint)f2bf(Wr[(2 * r + 1) * PHI_DIM + f]) << 16) | f2bf(Wr[(2 * r) * PHI_DIM + f]);
    uint b = ((uint)f2bf(Wr[(2 * r + 1) * PHI_DIM + f + 128]) << 16) |
             f2bf(Wr[(2 * r) * PHI_DIM + f + 128]);
    uint c = ((uint)f2bf(Wr[(2 * r + 1) * PHI_DIM + f + 256]) << 16) |
             f2bf(Wr[(2 * r) * PHI_DIM + f + 256]);
    wrA[r] = __builtin_bit_cast(bf16x2, a);
    wrB[r] = __builtin_bit_cast(bf16x2, b);
    wrC[r] = __builtin_bit_cast(bf16x2, c);
  }
  wrA[10] = __builtin_bit_cast(bf16x2, (uint)f2bf(br[f]));
  wrB[10] = __builtin_bit_cast(bf16x2, (uint)f2bf(br[f + 128]));
  wrC[10] = __builtin_bit_cast(bf16x2, (uint)f2bf(br[f + 256]));
#else
  float wrA[22], wrB[22], wrC[22];
#pragma unroll
  for (int r = 0; r < NRBF; r++) {
    wrA[r] = Wr[r * PHI_DIM + f];
    wrB[r] = Wr[r * PHI_DIM + f + 128];
    wrC[r] = Wr[r * PHI_DIM + f + 256];
  }
  wrA[20] = br[f];       wrA[21] = 0.f;
  wrB[20] = br[f + 128]; wrB[21] = 0.f;
  wrC[20] = br[f + 256]; wrC[21] = 0.f;
#endif
  const int n = blockIdx.x;
  const int f4 = f * 4;
  float ss = 0.f, ax = 0.f, ay = 0.f, az = 0.f;
  int cnt = 0;

  auto process = [&](uint4 e0, uint4 e1, uint4 e2, uint d0, uint d1, uint zu) {
    uint rbp[11] = {e0.y, e0.z, e0.w, e1.x, e1.y, e1.z, e1.w, e2.x, e2.y, e2.z, e2.w};
    const float dx = bflo(e0.x);
    const float dy = bfhi(e0.x);
    const float dz = bfhi(rbp[10]);
    float g0 = 0.f, g1 = 0.f, g2 = 0.f;
#if USE_DOT2
#pragma unroll
    for (int r = 0; r < 11; r++) {
      bf16x2 rp = __builtin_bit_cast(bf16x2, rbp[r]);
      g0 = __builtin_amdgcn_fdot2_f32_bf16(rp, wrA[r], g0, false);
      g1 = __builtin_amdgcn_fdot2_f32_bf16(rp, wrB[r], g1, false);
      g2 = __builtin_amdgcn_fdot2_f32_bf16(rp, wrC[r], g2, false);
    }
#else
#pragma unroll
    for (int r = 0; r < 11; r++) {
      float rlo = bflo(rbp[r]);
      float rhi = bfhi(rbp[r]);
      g0 += rlo * wrA[2 * r] + rhi * wrA[2 * r + 1];
      g1 += rlo * wrB[2 * r] + rhi * wrB[2 * r + 1];
      g2 += rlo * wrC[2 * r] + rhi * wrC[2 * r + 1];
    }
#endif
    const float vs = bflo(zu) * g2;
    ss += bfhi(d1) * g1;
    ax += bflo(d0) * g0 + vs * dx;
    ay += bfhi(d0) * g0 + vs * dy;
    az += bflo(d1) * g0 + vs * dz;
  };

  for (int b = 0; b < NBUCK; b++) {
    const int k0 = b * NN + n;
    const int beg = __builtin_amdgcn_readfirstlane(offsets[k0] + blocksums[k0 >> 8]);
    const int k1 = k0 + 1;
    const int end = __builtin_amdgcn_readfirstlane(
        (k1 < NKEY) ? (offsets[k1] + blocksums[k1 >> 8]) : offsets[NKEY]);
    cnt += end - beg;
    int p = beg;
    for (; p + 2 <= end; p += 2) {
      const int j0 = __builtin_amdgcn_readfirstlane(jlist[p]);
      const int j1 = __builtin_amdgcn_readfirstlane(jlist[p + 1]);
      const char* B0 = tab + (size_t)j0 * 1280;
      const char* B1 = tab + (size_t)j1 * 1280;
      const uint d00 = *(const uint*)(B0 + f4), d01 = *(const uint*)(B0 + 512 + f4);
      const uint z0 = *(const ushort*)(B0 + 1024 + f * 2);
      const uint d10 = *(const uint*)(B1 + f4), d11 = *(const uint*)(B1 + 512 + f4);
      const uint z1 = *(const ushort*)(B1 + 1024 + f * 2);
      const uint4* r0 = (const uint4*)(edata + (size_t)p * 12);
      const uint4* r1 = (const uint4*)(edata + (size_t)(p + 1) * 12);
      uint4 a0 = r0[0], a1 = r0[1], a2 = r0[2];
      uint4 b0 = r1[0], b1 = r1[1], b2 = r1[2];
      process(a0, a1, a2, d00, d01, z0);
      process(b0, b1, b2, d10, d11, z1);
    }
    if (p < end) {
      const int j0 = __builtin_amdgcn_readfirstlane(jlist[p]);
      const char* B0 = tab + (size_t)j0 * 1280;
      const uint d00 = *(const uint*)(B0 + f4), d01 = *(const uint*)(B0 + 512 + f4);
      const uint z0 = *(const ushort*)(B0 + 1024 + f * 2);
      const uint4* r0 = (const uint4*)(edata + (size_t)p * 12);
      process(r0[0], r0[1], r0[2], d00, d01, z0);
    }
  }

  const float inv = 1.0f / (float)cnt;
  out[(size_t)n * FDIM + f] = sf[(size_t)n * FDIM + f] + ss * inv;
  float* ov = out + (size_t)NN * FDIM + (size_t)n * (FDIM * 3) + f * 3;
  const float* iv = vf + (size_t)n * (FDIM * 3) + f * 3;
  ov[0] = iv[0] + ax * inv;
  ov[1] = iv[1] + ay * inv;
  ov[2] = iv[2] + az * inv;
}

extern "C" void kernel_launch(void* const* d_in, const int* in_sizes, int n_in,
                              void* d_out, int out_size, void* d_ws, size_t ws_size,
                              hipStream_t stream) {
  const int* idx_i = (const int*)d_in[0];
  const int* idx_j = (const int*)d_in[1];
  const float* rel_dir = (const float*)d_in[2];
  const float* cut = (const float*)d_in[3];
  const float* rbf = (const float*)d_in[4];
  const float* sf = (const float*)d_in[5];
  const float* vf = (const float*)d_in[6];
  const float* W1 = (const float*)d_in[7];
  const float* b1 = (const float*)d_in[8];
  const float* W2 = (const float*)d_in[9];
  const float* b2 = (const float*)d_in[10];
  const float* Wr = (const float*)d_in[11];
  const float* br = (const float*)d_in[12];
  float* out = (float*)d_out;

  // workspace layout (bytes):
  //   counts   : [0, 163840)            40960 ints (zero-padded; consumed by stage)
  //   offsets  : [163840, 327680)       40001 ints (PARTIAL; +blocksums[k>>8])
  //   blocksums: [327680, 328704)       256 ints
  //   edata    : [328704, 15688704)     320000 * 48 B
  //   tab      : [15688704, 28488704)   10000 * 1280 B
  //   jlist    : [28488704, 29768704)   320000 ints
  //   W1p      : [29768704, 29801472)   16384 ushort frag-packed
  //   W2p      : [29801472, 29899776)   49152 ushort frag-packed
  char* w = (char*)d_ws;
  int* counts = (int*)w;
  int* offsets = (int*)(w + 163840);
  int* blocksums = (int*)(w + 327680);
  uint* edata = (uint*)(w + 328704);
  char* tab = w + 15688704;
  int* jlist = (int*)(w + 28488704);
  ushort* W1p = (ushort*)(w + 29768704);
  ushort* W2p = (ushort*)(w + 29801472);

  hipMemsetAsync(w, 0, 163840, stream);  // zero counts only
  hipLaunchKernelGGL(wconv_kernel, dim3(32), dim3(256), 0, stream, W1, W2, W1p, W2p);
  hipLaunchKernelGGL(phi_kernel, dim3(NN / 16), dim3(256), 0, stream, sf, b1, b2, vf, idx_i,
                     idx_j, counts, W1p, W2p, tab);
  hipLaunchKernelGGL(scan1_kernel, dim3(SCAN_BLOCKS), dim3(256), 0, stream, counts, offsets,
                     blocksums);
  hipLaunchKernelGGL(scan2_kernel, dim3(1), dim3(256), 0, stream, blocksums, offsets);
  hipLaunchKernelGGL(stage_kernel, dim3((NE + 255) / 256), dim3(256), 0, stream, idx_i, idx_j,
                     cut, rel_dir, rbf, offsets, blocksums, counts, edata, jlist);
  hipLaunchKernelGGL(node_kernel, dim3(NN), dim3(128), 0, stream, edata, jlist, Wr, br, tab, sf,
                     vf, offsets, blocksums, out);
}

// Round 27
// 136.675 us; speedup vs baseline: 1.0080x; 1.0080x over previous
//
#include <hip/hip_runtime.h>
#include <hip/hip_bf16.h>

#define NN 10000
#define NE 320000
#define FDIM 128
#define NRBF 20
#define PHI_DIM 384
#define NBUCK 4
#define NKEY (NN * NBUCK)     // 40000, key = bucket*NN + i (bucket-major)
#define SCAN_BLOCKS 157       // 157*256 = 40192 >= NKEY+1

typedef unsigned int uint;
typedef unsigned short ushort;
typedef __bf16 bf16x8 __attribute__((ext_vector_type(8)));
typedef float f32x4 __attribute__((ext_vector_type(4)));

#if __has_builtin(__builtin_amdgcn_fdot2_f32_bf16)
#define USE_DOT2 1
typedef __bf16 bf16x2 __attribute__((ext_vector_type(2)));
#else
#define USE_DOT2 0
#endif

__device__ __forceinline__ ushort f2bf(float x) {
  __hip_bfloat16 b = __float2bfloat16(x);
  return *(ushort*)&b;
}
__device__ __forceinline__ float bflo(uint u) { return __uint_as_float(u << 16); }
__device__ __forceinline__ float bfhi(uint u) { return __uint_as_float(u & 0xffff0000u); }
__device__ __forceinline__ float bf2f(ushort u) { return __uint_as_float(((uint)u) << 16); }
__device__ __forceinline__ int jbucket(int j) { return (int)(((uint)j * NBUCK) / NN); }

// tab row (1280 B): [0,512) uint wy|wx ; [512,1024) uint phi1|wz ; [1024,1280) ushort phi2
// edata record (48 B): dword0 = dy|dx ; dword1..10 = (rbf*c) pairs ; dword11 = dz|c
// offsets[] PARTIAL (within-scan1-block); final = offsets[k] + blocksums[k>>8];
// offsets[NKEY] written FINAL by scan2.
// W1p/W2p: frag-packed bf16 weights: [(ks*4+g)*COLS + n] -> 8 bf16 of rows ks*32+g*8+e.

// ---------------- weight pre-pack: f32 -> frag-friendly bf16 ----------------
__global__ void wconv_kernel(const float* __restrict__ W1, const float* __restrict__ W2,
                             ushort* __restrict__ W1p, ushort* __restrict__ W2p) {
  const int gid = blockIdx.x * 256 + threadIdx.x;  // 8192 total
  if (gid < 2048) {  // W1: 4*4*128 groups
    const int n = gid & 127, g = (gid >> 7) & 3, ks = gid >> 9;
    ushort* dst = W1p + gid * 8;
#pragma unroll
    for (int e = 0; e < 8; e++) dst[e] = f2bf(W1[(ks * 32 + g * 8 + e) * FDIM + n]);
  } else {  // W2: 4*4*384 groups
    const int q = gid - 2048;
    const int ks = q / 1536;
    const int rem = q - ks * 1536;
    const int g = rem / 384;
    const int n = rem - g * 384;
    ushort* dst = W2p + q * 8;
#pragma unroll
    for (int e = 0; e < 8; e++) dst[e] = f2bf(W2[(ks * 32 + g * 8 + e) * PHI_DIM + n]);
  }
}

// ------- node MLP via MFMA: 625 blocks x 256 thr (4 waves), 16 nodes/block -------
// A layout (verified r17): row=lane&15, k=(lane>>4)*8+[0,8) ; B: col=lane&15, same k
// D: col=lane&15, row=(lane>>4)*4+reg
__global__ __launch_bounds__(256) void phi_kernel(
    const float* __restrict__ S, const float* __restrict__ b1, const float* __restrict__ b2,
    const float* __restrict__ vf, const int* __restrict__ idx_i, const int* __restrict__ idx_j,
    int* __restrict__ counts, const ushort* __restrict__ W1p, const ushort* __restrict__ W2p,
    char* __restrict__ tab) {
  __shared__ ushort Hb[16][136];  // padded: row stride 272 B
  __shared__ ushort Pb[16][392];  // padded: row stride 784 B
  const int t = threadIdx.x;
  const int lane = t & 63;
  const int wv = t >> 6;        // 0..3
  const int mrow = lane & 15;   // A-row (node) / B,D-col
  const int kg = lane >> 4;     // 0..3 (k-group)
  // fused: edge counting (2 edges/thread: 625*256*2 == NE)
  {
    const int e0 = (blockIdx.x * 256 + t) * 2;
    atomicAdd(&counts[jbucket(idx_j[e0]) * NN + idx_i[e0]], 1);
    atomicAdd(&counts[jbucket(idx_j[e0 + 1]) * NN + idx_i[e0 + 1]], 1);
  }
  const int n0 = blockIdx.x * 16;
  // A-frags from S (f32 -> bf16)
  bf16x8 sfrag[4];
#pragma unroll
  for (int ks = 0; ks < 4; ks++) {
    const float* sp = S + (size_t)(n0 + mrow) * FDIM + ks * 32 + kg * 8;
    float4 v0 = *(const float4*)sp;
    float4 v1 = *(const float4*)(sp + 4);
    uint w0 = ((uint)f2bf(v0.y) << 16) | f2bf(v0.x);
    uint w1 = ((uint)f2bf(v0.w) << 16) | f2bf(v0.z);
    uint w2 = ((uint)f2bf(v1.y) << 16) | f2bf(v1.x);
    uint w3 = ((uint)f2bf(v1.w) << 16) | f2bf(v1.z);
    sfrag[ks] = __builtin_bit_cast(bf16x8, make_uint4(w0, w1, w2, w3));
  }
  // layer 1: H = silu(S@W1 + b1), wave wv computes feat cols [wv*32, wv*32+32)
#pragma unroll
  for (int tile = 0; tile < 2; tile++) {
    const int nc = wv * 32 + tile * 16 + mrow;  // feature col
    f32x4 acc = {0.f, 0.f, 0.f, 0.f};
#pragma unroll
    for (int ks = 0; ks < 4; ks++) {
      bf16x8 bfrag = __builtin_bit_cast(
          bf16x8, *(const uint4*)(W1p + ((size_t)(ks * 4 + kg) * FDIM + nc) * 8));
      acc = __builtin_amdgcn_mfma_f32_16x16x32_bf16(sfrag[ks], bfrag, acc, 0, 0, 0);
    }
    const float bb = b1[nc];
#pragma unroll
    for (int r = 0; r < 4; r++) {
      const float x = acc[r] + bb;
      Hb[kg * 4 + r][nc] = f2bf(x / (1.0f + expf(-x)));
    }
  }
  __syncthreads();
  // layer 2: phi = H@W2 + b2, wave wv computes cols [wv*96, wv*96+96)
  bf16x8 hfrag[4];
#pragma unroll
  for (int ks = 0; ks < 4; ks++)
    hfrag[ks] = __builtin_bit_cast(bf16x8, *(const uint4*)&Hb[mrow][ks * 32 + kg * 8]);
#pragma unroll
  for (int tile = 0; tile < 6; tile++) {
    const int nc = wv * 96 + tile * 16 + mrow;  // phi col 0..383
    f32x4 acc = {0.f, 0.f, 0.f, 0.f};
#pragma unroll
    for (int ks = 0; ks < 4; ks++) {
      bf16x8 bfrag = __builtin_bit_cast(
          bf16x8, *(const uint4*)(W2p + ((size_t)(ks * 4 + kg) * PHI_DIM + nc) * 8));
      acc = __builtin_amdgcn_mfma_f32_16x16x32_bf16(hfrag[ks], bfrag, acc, 0, 0, 0);
    }
    const float bb = b2[nc];
#pragma unroll
    for (int r = 0; r < 4; r++) Pb[kg * 4 + r][nc] = f2bf(acc[r] + bb);
  }
  __syncthreads();
  // pack phase: w* = vf*·phi0 precompute + tab row assembly (16 nodes x 128 feats)
#pragma unroll
  for (int c = 0; c < 8; c++) {
    const int idx = c * 256 + t;
    const int nd = idx >> 7;
    const int f = idx & 127;
    const int node = n0 + nd;
    const float p0 = bf2f(Pb[nd][f]);
    const uint p1u = Pb[nd][f + 128];
    const ushort p2u = Pb[nd][f + 256];
    const float* src = vf + (size_t)node * (FDIM * 3) + f * 3;
    const uint wx = f2bf(src[0] * p0);
    const uint wy = f2bf(src[1] * p0);
    const uint wz = f2bf(src[2] * p0);
    char* pb = tab + (size_t)node * 1280;
    ((uint*)pb)[f] = (wy << 16) | wx;
    ((uint*)(pb + 512))[f] = (p1u << 16) | wz;
    ((ushort*)(pb + 1024))[f] = p2u;
  }
}

// ---------------- scan: per-block partials + block-sum scan ----------------
__global__ void scan1_kernel(const int* __restrict__ counts, int* __restrict__ offsets,
                             int* __restrict__ blocksums) {
  __shared__ int s[256];
  const int t = threadIdx.x;
  const int idx = blockIdx.x * 256 + t;
  const int c = counts[idx];  // region zero-padded to 40960
  s[t] = c;
  __syncthreads();
  for (int off = 1; off < 256; off <<= 1) {
    int v = (t >= off) ? s[t - off] : 0;
    __syncthreads();
    s[t] += v;
    __syncthreads();
  }
  if (idx < NKEY) offsets[idx] = s[t] - c;  // exclusive WITHIN block (partial)
  if (t == 255) blocksums[blockIdx.x] = s[255];
}

__global__ void scan2_kernel(int* __restrict__ blocksums, int* __restrict__ offsets) {
  __shared__ int s[256];
  const int t = threadIdx.x;  // 256 threads
  int v0 = (t < SCAN_BLOCKS) ? blocksums[t] : 0;
  s[t] = v0;
  __syncthreads();
  for (int off = 1; off < 256; off <<= 1) {
    int v = (t >= off) ? s[t - off] : 0;
    __syncthreads();
    s[t] += v;
    __syncthreads();
  }
  if (t < SCAN_BLOCKS) blocksums[t] = s[t] - v0;  // exclusive base per block
  if (t == 255) offsets[NKEY] = s[t];             // FINAL total = NE
}

// ---------------- stage CSR-ordered (bucket-major): jlist + 48-B records ----------------
__global__ void stage_kernel(const int* __restrict__ idx_i, const int* __restrict__ idx_j,
                             const float* __restrict__ cut, const float* __restrict__ dir,
                             const float* __restrict__ rbf, const int* __restrict__ offsets,
                             const int* __restrict__ blocksums, int* __restrict__ counts,
                             uint* __restrict__ edata, int* __restrict__ jlist) {
  int e = blockIdx.x * blockDim.x + threadIdx.x;
  if (e >= NE) return;
  const int j = idx_j[e];
  const int key = jbucket(j) * NN + idx_i[e];
  int pos = atomicSub(&counts[key], 1) - 1;
  const int slot = offsets[key] + blocksums[key >> 8] + pos;
  jlist[slot] = j;
  const float c = cut[e];
  uint w[12];
  w[0] = ((uint)f2bf(dir[e * 3 + 1]) << 16) | f2bf(dir[e * 3 + 0]);
  const float* rb = rbf + (size_t)e * NRBF;
#pragma unroll
  for (int r = 0; r < 10; r++) {
    uint lo = (uint)f2bf(rb[2 * r] * c);
    uint hi = (uint)f2bf(rb[2 * r + 1] * c);
    w[1 + r] = (hi << 16) | lo;
  }
  w[11] = ((uint)f2bf(dir[e * 3 + 2]) << 16) | f2bf(c);
  uint4* d = (uint4*)(edata + (size_t)slot * 12);
  d[0] = make_uint4(w[0], w[1], w[2], w[3]);
  d[1] = make_uint4(w[4], w[5], w[6], w[7]);
  d[2] = make_uint4(w[8], w[9], w[10], w[11]);
}

// ---- node: 1 node / 128-thread block, 4 bucket-segments, 2-deep pipeline ----
__global__ __launch_bounds__(128, 5) void node_kernel(
    const uint* __restrict__ edata, const int* __restrict__ jlist,
    const float* __restrict__ Wr, const float* __restrict__ br,
    const char* __restrict__ tab, const float* __restrict__ sf,
    const float* __restrict__ vf, const int* __restrict__ offsets,
    const int* __restrict__ blocksums, float* __restrict__ out) {
  const int f = threadIdx.x;  // 0..127
#if USE_DOT2
  bf16x2 wrA[11], wrB[11], wrC[11];
#pragma unroll
  for (int r = 0; r < 10; r++) {
    uint a = ((uint)f2bf(Wr[(2 * r + 1) * PHI_DIM + f]) << 16) | f2bf(Wr[(2 * r) * PHI_DIM + f]);
    uint b = ((uint)f2bf(Wr[(2 * r + 1) * PHI_DIM + f + 128]) << 16) |
             f2bf(Wr[(2 * r) * PHI_DIM + f + 128]);
    uint c = ((uint)f2bf(Wr[(2 * r + 1) * PHI_DIM + f + 256]) << 16) |
             f2bf(Wr[(2 * r) * PHI_DIM + f + 256]);
    wrA[r] = __builtin_bit_cast(bf16x2, a);
    wrB[r] = __builtin_bit_cast(bf16x2, b);
    wrC[r] = __builtin_bit_cast(bf16x2, c);
  }
  wrA[10] = __builtin_bit_cast(bf16x2, (uint)f2bf(br[f]));
  wrB[10] = __builtin_bit_cast(bf16x2, (uint)f2bf(br[f + 128]));
  wrC[10] = __builtin_bit_cast(bf16x2, (uint)f2bf(br[f + 256]));
#else
  float wrA[22], wrB[22], wrC[22];
#pragma unroll
  for (int r = 0; r < NRBF; r++) {
    wrA[r] = Wr[r * PHI_DIM + f];
    wrB[r] = Wr[r * PHI_DIM + f + 128];
    wrC[r] = Wr[r * PHI_DIM + f + 256];
  }
  wrA[20] = br[f];       wrA[21] = 0.f;
  wrB[20] = br[f + 128]; wrB[21] = 0.f;
  wrC[20] = br[f + 256]; wrC[21] = 0.f;
#endif
  const int n = blockIdx.x;
  const int f4 = f * 4;
  float ss = 0.f, ax = 0.f, ay = 0.f, az = 0.f;
  int cnt = 0;

  auto process = [&](uint4 e0, uint4 e1, uint4 e2, uint d0, uint d1, uint zu) {
    uint rbp[11] = {e0.y, e0.z, e0.w, e1.x, e1.y, e1.z, e1.w, e2.x, e2.y, e2.z, e2.w};
    const float dx = bflo(e0.x);
    const float dy = bfhi(e0.x);
    const float dz = bfhi(rbp[10]);
    float g0 = 0.f, g1 = 0.f, g2 = 0.f;
#if USE_DOT2
#pragma unroll
    for (int r = 0; r < 11; r++) {
      bf16x2 rp = __builtin_bit_cast(bf16x2, rbp[r]);
      g0 = __builtin_amdgcn_fdot2_f32_bf16(rp, wrA[r], g0, false);
      g1 = __builtin_amdgcn_fdot2_f32_bf16(rp, wrB[r], g1, false);
      g2 = __builtin_amdgcn_fdot2_f32_bf16(rp, wrC[r], g2, false);
    }
#else
#pragma unroll
    for (int r = 0; r < 11; r++) {
      float rlo = bflo(rbp[r]);
      float rhi = bfhi(rbp[r]);
      g0 += rlo * wrA[2 * r] + rhi * wrA[2 * r + 1];
      g1 += rlo * wrB[2 * r] + rhi * wrB[2 * r + 1];
      g2 += rlo * wrC[2 * r] + rhi * wrC[2 * r + 1];
    }
#endif
    const float vs = bflo(zu) * g2;
    ss += bfhi(d1) * g1;
    ax += bflo(d0) * g0 + vs * dx;
    ay += bfhi(d0) * g0 + vs * dy;
    az += bflo(d1) * g0 + vs * dz;
  };

  for (int b = 0; b < NBUCK; b++) {
    const int k0 = b * NN + n;
    const int beg = __builtin_amdgcn_readfirstlane(offsets[k0] + blocksums[k0 >> 8]);
    const int k1 = k0 + 1;
    const int end = __builtin_amdgcn_readfirstlane(
        (k1 < NKEY) ? (offsets[k1] + blocksums[k1 >> 8]) : offsets[NKEY]);
    cnt += end - beg;
    int p = beg;
    for (; p + 2 <= end; p += 2) {
      const int j0 = __builtin_amdgcn_readfirstlane(jlist[p]);
      const int j1 = __builtin_amdgcn_readfirstlane(jlist[p + 1]);
      const char* B0 = tab + (size_t)j0 * 1280;
      const char* B1 = tab + (size_t)j1 * 1280;
      const uint d00 = *(const uint*)(B0 + f4), d01 = *(const uint*)(B0 + 512 + f4);
      const uint z0 = *(const ushort*)(B0 + 1024 + f * 2);
      const uint d10 = *(const uint*)(B1 + f4), d11 = *(const uint*)(B1 + 512 + f4);
      const uint z1 = *(const ushort*)(B1 + 1024 + f * 2);
      const uint4* r0 = (const uint4*)(edata + (size_t)p * 12);
      const uint4* r1 = (const uint4*)(edata + (size_t)(p + 1) * 12);
      uint4 a0 = r0[0], a1 = r0[1], a2 = r0[2];
      uint4 b0 = r1[0], b1 = r1[1], b2 = r1[2];
      process(a0, a1, a2, d00, d01, z0);
      process(b0, b1, b2, d10, d11, z1);
    }
    if (p < end) {
      const int j0 = __builtin_amdgcn_readfirstlane(jlist[p]);
      const char* B0 = tab + (size_t)j0 * 1280;
      const uint d00 = *(const uint*)(B0 + f4), d01 = *(const uint*)(B0 + 512 + f4);
      const uint z0 = *(const ushort*)(B0 + 1024 + f * 2);
      const uint4* r0 = (const uint4*)(edata + (size_t)p * 12);
      process(r0[0], r0[1], r0[2], d00, d01, z0);
    }
  }

  const float inv = 1.0f / (float)cnt;
  out[(size_t)n * FDIM + f] = sf[(size_t)n * FDIM + f] + ss * inv;
  float* ov = out + (size_t)NN * FDIM + (size_t)n * (FDIM * 3) + f * 3;
  const float* iv = vf + (size_t)n * (FDIM * 3) + f * 3;
  ov[0] = iv[0] + ax * inv;
  ov[1] = iv[1] + ay * inv;
  ov[2] = iv[2] + az * inv;
}

extern "C" void kernel_launch(void* const* d_in, const int* in_sizes, int n_in,
                              void* d_out, int out_size, void* d_ws, size_t ws_size,
                              hipStream_t stream) {
  const int* idx_i = (const int*)d_in[0];
  const int* idx_j = (const int*)d_in[1];
  const float* rel_dir = (const float*)d_in[2];
  const float* cut = (const float*)d_in[3];
  const float* rbf = (const float*)d_in[4];
  const float* sf = (const float*)d_in[5];
  const float* vf = (const float*)d_in[6];
  const float* W1 = (const float*)d_in[7];
  const float* b1 = (const float*)d_in[8];
  const float* W2 = (const float*)d_in[9];
  const float* b2 = (const float*)d_in[10];
  const float* Wr = (const float*)d_in[11];
  const float* br = (const float*)d_in[12];
  float* out = (float*)d_out;

  // workspace layout (bytes):
  //   counts   : [0, 163840)            40960 ints (zero-padded; consumed by stage)
  //   offsets  : [163840, 327680)       40001 ints (PARTIAL; +blocksums[k>>8])
  //   blocksums: [327680, 328704)       256 ints
  //   edata    : [328704, 15688704)     320000 * 48 B
  //   tab      : [15688704, 28488704)   10000 * 1280 B
  //   jlist    : [28488704, 29768704)   320000 ints
  //   W1p      : [29768704, 29801472)   16384 ushort frag-packed
  //   W2p      : [29801472, 29899776)   49152 ushort frag-packed
  char* w = (char*)d_ws;
  int* counts = (int*)w;
  int* offsets = (int*)(w + 163840);
  int* blocksums = (int*)(w + 327680);
  uint* edata = (uint*)(w + 328704);
  char* tab = w + 15688704;
  int* jlist = (int*)(w + 28488704);
  ushort* W1p = (ushort*)(w + 29768704);
  ushort* W2p = (ushort*)(w + 29801472);

  hipMemsetAsync(w, 0, 163840, stream);  // zero counts only
  hipLaunchKernelGGL(wconv_kernel, dim3(32), dim3(256), 0, stream, W1, W2, W1p, W2p);
  hipLaunchKernelGGL(phi_kernel, dim3(NN / 16), dim3(256), 0, stream, sf, b1, b2, vf, idx_i,
                     idx_j, counts, W1p, W2p, tab);
  hipLaunchKernelGGL(scan1_kernel, dim3(SCAN_BLOCKS), dim3(256), 0, stream, counts, offsets,
                     blocksums);
  hipLaunchKernelGGL(scan2_kernel, dim3(1), dim3(256), 0, stream, blocksums, offsets);
  hipLaunchKernelGGL(stage_kernel, dim3((NE + 255) / 256), dim3(256), 0, stream, idx_i, idx_j,
                     cut, rel_dir, rbf, offsets, blocksums, counts, edata, jlist);
  hipLaunchKernelGGL(node_kernel, dim3(NN), dim3(128), 0, stream, edata, jlist, Wr, br, tab, sf,
                     vf, offsets, blocksums, out);
}